// Round 4
// baseline (186.078 us; speedup 1.0000x reference)
//
#include <hip/hip_runtime.h>

// Dims
#define B_   1024
#define S_   128
#define LP_  14
#define K_   3
#define CE_  6
#define WE_  10
#define LF_  4
#define H_   6
#define D_   14
#define T_   135
#define LW_  12
#define V_   50000
#define A_   100
#define NSEQ (B_ * 2)   // 2048 independent (sentence, direction) recurrences

// Fast overflow-safe sigmoid/tanh (inf-propagation gives correct saturation).
static __device__ __forceinline__ float fsigm(float x) {
    return __frcp_rn(1.0f + __expf(-x));
}
static __device__ __forceinline__ float ftanh(float x) {
    return fmaf(2.0f, __frcp_rn(1.0f + __expf(-2.0f * x)), -1.0f);
}

// Wave64 all-lane sum via DPP (no DS traffic).
static __device__ __forceinline__ float wave_sum64(float s) {
    int v = __float_as_int(s);
    float f;
    f = __int_as_float(__builtin_amdgcn_update_dpp(0, v, 0xB1, 0xF, 0xF, true));  s += f; v = __float_as_int(s);
    f = __int_as_float(__builtin_amdgcn_update_dpp(0, v, 0x4E, 0xF, 0xF, true));  s += f; v = __float_as_int(s);
    f = __int_as_float(__builtin_amdgcn_update_dpp(0, v, 0x141, 0xF, 0xF, true)); s += f; v = __float_as_int(s);
    f = __int_as_float(__builtin_amdgcn_update_dpp(0, v, 0x140, 0xF, 0xF, true)); s += f; v = __float_as_int(s);
    f = __int_as_float(__builtin_amdgcn_update_dpp(0, v, 0x142, 0xA, 0xF, true)); s += f; v = __float_as_int(s);
    f = __int_as_float(__builtin_amdgcn_update_dpp(0, v, 0x143, 0xC, 0xF, true)); s += f; v = __float_as_int(s);
    return __int_as_float(__builtin_amdgcn_readlane(v, 63));
}

// ---------------- Kernel 1a: char CNN + embeddings + gate pre-activations (throughput) ----
// gbuf layout: [s][seq][unit u][gate j] -- UNIT-MAJOR so k_l reads ONE float4 per step.
// seq = 2*b + dir. 96 B per record, float4-aligned.
__global__ __launch_bounds__(256) void k_e(
    const int* __restrict__ word_idx, const int* __restrict__ char_idx,
    const float* __restrict__ word_emb, const float* __restrict__ char_emb,
    const float* __restrict__ Wc, const float* __restrict__ bc,
    const float* __restrict__ Wih_f, const float* __restrict__ b_f,
    const float* __restrict__ Wih_b, const float* __restrict__ b_b,
    float* __restrict__ gbuf)
{
    __shared__ float s_ce[A_ * CE_];
    __shared__ float s_wc[LF_ * K_ * CE_];
    __shared__ float s_bc[LF_];
    int t = threadIdx.x;
    for (int e = t; e < A_ * CE_; e += 256) s_ce[e] = char_emb[e];
    if (t < LF_ * K_ * CE_) s_wc[t] = Wc[t];
    if (t < LF_) s_bc[t] = bc[t];
    __syncthreads();

    int wid = blockIdx.x * 256 + t;     // 0 .. 131071
    int s = wid >> 10;                  // 0 .. 127
    int b = wid & 1023;                 // 0 .. 1023
    int w = b * S_ + s;                 // row in word_idx/char_idx

    const int2* ci2 = (const int2*)(char_idx + (size_t)w * LP_);   // w*56B, 8B-aligned
    int idxs[LP_];
    #pragma unroll
    for (int p = 0; p < 7; ++p) {
        int2 v = ci2[p];
        idxs[2 * p] = v.x; idxs[2 * p + 1] = v.y;
    }
    float ce[LP_][CE_];
    #pragma unroll
    for (int p = 0; p < LP_; ++p) {
        int idx = idxs[p];
        idx = idx < 0 ? 0 : (idx >= A_ ? A_ - 1 : idx);
        #pragma unroll
        for (int c = 0; c < CE_; ++c) ce[p][c] = s_ce[idx * CE_ + c];
    }
    float x[D_];
    #pragma unroll
    for (int l = 0; l < LF_; ++l) {
        float acc[LW_];
        float bl = s_bc[l];
        #pragma unroll
        for (int q = 0; q < LW_; ++q) acc[q] = bl;
        #pragma unroll
        for (int kk = 0; kk < K_; ++kk) {
            #pragma unroll
            for (int c = 0; c < CE_; ++c) {
                float wv_ = s_wc[l * (K_ * CE_) + kk * CE_ + c];
                #pragma unroll
                for (int q = 0; q < LW_; ++q) acc[q] = fmaf(ce[q + kk][c], wv_, acc[q]);
            }
        }
        float m = acc[0];
        #pragma unroll
        for (int q = 1; q < LW_; ++q) m = fmaxf(m, acc[q]);
        x[WE_ + l] = m;
    }
    int wi = word_idx[w];
    wi = wi < 0 ? 0 : (wi >= V_ ? V_ - 1 : wi);
    const float2* wep = (const float2*)(word_emb + (size_t)wi * WE_);  // wi*40B, 8B-aligned
    #pragma unroll
    for (int c = 0; c < WE_ / 2; ++c) {
        float2 v = wep[c];
        x[2 * c] = v.x; x[2 * c + 1] = v.y;
    }

    // Gate pre-activations; record float4 #u = (i, f, g, o) of unit u (rows u, 6+u, 12+u, 18+u).
    float* dst = gbuf + ((size_t)s * NSEQ + 2 * b) * 24;   // fwd at +0, bwd at +24
    {
        float g[24];
        #pragma unroll
        for (int r = 0; r < 24; ++r) {
            float a = b_f[r];
            #pragma unroll
            for (int k = 0; k < D_; ++k) a = fmaf(Wih_f[r * D_ + k], x[k], a);
            g[r] = a;
        }
        #pragma unroll
        for (int u = 0; u < H_; ++u)
            ((float4*)dst)[u] = make_float4(g[u], g[H_ + u], g[2 * H_ + u], g[3 * H_ + u]);
    }
    {
        float g[24];
        #pragma unroll
        for (int r = 0; r < 24; ++r) {
            float a = b_b[r];
            #pragma unroll
            for (int k = 0; k < D_; ++k) a = fmaf(Wih_b[r * D_ + k], x[k], a);
            g[r] = a;
        }
        #pragma unroll
        for (int u = 0; u < H_; ++u)
            ((float4*)(dst + 24))[u] = make_float4(g[u], g[H_ + u], g[2 * H_ + u], g[3 * H_ + u]);
    }
}

// ---------------- Kernel 1b: BiLSTM recurrence (latency-optimized, readlane broadcast) ----
// Wave = one sentence: lanes 0-5 = fwd units, lanes 32-37 = bwd units (others shadow u=5).
// 1024 waves = 1 wave/SIMD chip-wide. h-broadcast via v_readlane (SGPR, scalar pipe,
// ~20cy) + cndmask select -- replaces 6x ds_bpermute (~110cy DS latency) on the per-step
// critical path. Gate dots split into two 3-FMA chains. One float4 load/step, 8-deep ring.
__global__ __launch_bounds__(64) void k_l(
    const float* __restrict__ Whh_f, const float* __restrict__ Whh_b,
    const float* __restrict__ gbuf, float* __restrict__ hbuf)
{
    int lane = threadIdx.x;
    int dir  = lane >> 5;
    int u32  = lane & 31;
    bool act = (u32 < H_);
    int u    = act ? u32 : (H_ - 1);
    int b    = blockIdx.x;               // sentence
    int seq  = 2 * b + dir;

    const float* Whh = dir ? Whh_b : Whh_f;
    float w0[H_], w1[H_], w2[H_], w3[H_];
    #pragma unroll
    for (int k = 0; k < H_; ++k) {
        w0[k] = Whh[(0 * H_ + u) * H_ + k];
        w1[k] = Whh[(1 * H_ + u) * H_ + k];
        w2[k] = Whh[(2 * H_ + u) * H_ + k];
        w3[k] = Whh[(3 * H_ + u) * H_ + k];
    }

    const long gstride = (dir ? -1L : 1L) * (long)(NSEQ * 24);
    const float* gp = gbuf + ((size_t)(dir ? S_ - 1 : 0) * NSEQ + (size_t)seq) * 24 + u * 4;

    // 8-deep prefetch ring (static indexing -> VGPRs)
    float4 pf[8];
    #pragma unroll
    for (int j = 0; j < 8; ++j) pf[j] = *(const float4*)(gp + j * gstride);
    const float* gn = gp + 8 * gstride;

    float* hp = hbuf + ((size_t)b * S_ + (size_t)(dir ? S_ - 1 : 0)) * 12 + dir * H_ + u;
    const int hstride = dir ? -12 : 12;

    float h[H_];
    #pragma unroll
    for (int k = 0; k < H_; ++k) h[k] = 0.f;
    float c = 0.f;

    for (int m = 0; m < S_; m += 8) {
        #pragma unroll
        for (int j = 0; j < 8; ++j) {
            float4 g4 = pf[j];
            if (m + 8 + j < S_) {            // uniform branch; refill ring 8 steps ahead
                pf[j] = *(const float4*)gn;
                gn += gstride;
            }
            // split-accumulator dots: chain 3 FMA + add instead of 6 FMA
            float ai0 = fmaf(w0[0], h[0], g4.x); ai0 = fmaf(w0[1], h[1], ai0); ai0 = fmaf(w0[2], h[2], ai0);
            float ai1 =      w0[3] * h[3];       ai1 = fmaf(w0[4], h[4], ai1); ai1 = fmaf(w0[5], h[5], ai1);
            float af0 = fmaf(w1[0], h[0], g4.y); af0 = fmaf(w1[1], h[1], af0); af0 = fmaf(w1[2], h[2], af0);
            float af1 =      w1[3] * h[3];       af1 = fmaf(w1[4], h[4], af1); af1 = fmaf(w1[5], h[5], af1);
            float ag0 = fmaf(w2[0], h[0], g4.z); ag0 = fmaf(w2[1], h[1], ag0); ag0 = fmaf(w2[2], h[2], ag0);
            float ag1 =      w2[3] * h[3];       ag1 = fmaf(w2[4], h[4], ag1); ag1 = fmaf(w2[5], h[5], ag1);
            float ao0 = fmaf(w3[0], h[0], g4.w); ao0 = fmaf(w3[1], h[1], ao0); ao0 = fmaf(w3[2], h[2], ao0);
            float ao1 =      w3[3] * h[3];       ao1 = fmaf(w3[4], h[4], ao1); ao1 = fmaf(w3[5], h[5], ao1);
            float si = fsigm(ai0 + ai1);
            float sf = fsigm(af0 + af1);
            float so = fsigm(ao0 + ao1);
            float tg = ftanh(ag0 + ag1);
            c = fmaf(sf, c, si * tg);
            float hu = so * ftanh(c);
            if (act) *hp = hu;
            hp += hstride;
            // Broadcast: readlane (scalar pipe) + per-half select. No DS ops.
            #pragma unroll
            for (int k = 0; k < H_; ++k) {
                int vf = __builtin_amdgcn_readlane(__float_as_int(hu), k);
                int vb = __builtin_amdgcn_readlane(__float_as_int(hu), 32 + k);
                h[k] = __int_as_float(dir ? vb : vf);
            }
        }
    }
}

// ---------------- Kernel 2: projection + log_softmax -> out f32 [B*S][135] ----------------
__global__ __launch_bounds__(256) void k_p(
    const float* __restrict__ hbuf,
    const float* __restrict__ Wt, const float* __restrict__ bt,
    float* __restrict__ out)
{
    __shared__ float s_hb[64 * 12];         // 3 KB
    int t = threadIdx.x;
    int ib = blockIdx.x * 64;               // first item of block
    {
        const float4* src = (const float4*)(hbuf + (size_t)ib * 12);
        float4* dst = (float4*)s_hb;
        if (t < 192) dst[t] = src[t];       // 64*12 floats = 192 float4, coalesced
    }
    __syncthreads();

    int lane = t & 63, wv = t >> 6;
    bool has2 = (lane < T_ - 128);
    int t2c = has2 ? (lane + 128) : (T_ - 1);

    float wA[12], wB[12], wC[12];
    #pragma unroll
    for (int jj = 0; jj < 12; ++jj) {
        wA[jj] = Wt[lane * 12 + jj];
        wB[jj] = Wt[(lane + 64) * 12 + jj];
        wC[jj] = Wt[t2c * 12 + jj];
    }
    float bA = bt[lane], bB = bt[lane + 64], bC = bt[t2c];

    int it0 = wv * 16;
    #pragma unroll 4
    for (int k = 0; k < 16; ++k) {
        int it = it0 + k;
        const float4* h4 = (const float4*)(s_hb + it * 12);   // broadcast LDS reads
        float4 a0 = h4[0], a1 = h4[1], a2 = h4[2];
        float hv[12] = {a0.x, a0.y, a0.z, a0.w, a1.x, a1.y, a1.z, a1.w, a2.x, a2.y, a2.z, a2.w};
        float y0 = bA, y1 = bB, y2 = bC;
        #pragma unroll
        for (int jj = 0; jj < 12; ++jj) {
            y0 = fmaf(hv[jj], wA[jj], y0);
            y1 = fmaf(hv[jj], wB[jj], y1);
            y2 = fmaf(hv[jj], wC[jj], y2);
        }
        // |y| small (h in (-1,1), weights ~0.1) -> exp safe without max-subtraction
        float ss = __expf(y0) + __expf(y1) + (has2 ? __expf(y2) : 0.0f);
        float ls = __logf(wave_sum64(ss));
        float* op = out + (size_t)(ib + it) * T_;
        op[lane]      = y0 - ls;
        op[lane + 64] = y1 - ls;
        if (has2) op[lane + 128] = y2 - ls;
    }
}

extern "C" void kernel_launch(void* const* d_in, const int* in_sizes, int n_in,
                              void* d_out, int out_size, void* d_ws, size_t ws_size,
                              hipStream_t stream)
{
    const int* word_idx = (const int*)d_in[0];
    const int* char_idx = (const int*)d_in[1];
    const float* word_emb = (const float*)d_in[2];
    const float* char_emb = (const float*)d_in[3];
    const float* Wc    = (const float*)d_in[4];
    const float* bc    = (const float*)d_in[5];
    const float* Wih_f = (const float*)d_in[6];
    const float* Whh_f = (const float*)d_in[7];
    const float* b_f   = (const float*)d_in[8];
    const float* Wih_b = (const float*)d_in[9];
    const float* Whh_b = (const float*)d_in[10];
    const float* b_b   = (const float*)d_in[11];
    const float* Wt    = (const float*)d_in[12];
    const float* bt    = (const float*)d_in[13];

    const size_t hbuf_fl = (size_t)B_ * S_ * 12;            // 6.3 MB
    const size_t gbuf_fl = (size_t)S_ * NSEQ * 24;          // 25.2 MB

    float* hbuf = (float*)d_ws;
    float* gbuf;
    if (ws_size >= (hbuf_fl + gbuf_fl) * sizeof(float)) {
        gbuf = (float*)d_ws + hbuf_fl;
    } else {
        // scratch inside d_out (70.8 MB): k_e writes, k_l reads, then k_p overwrites
        // every element of d_out. Stream-ordered, so this is safe.
        gbuf = (float*)d_out;
    }

    k_e<<<(B_ * S_) / 256, 256, 0, stream>>>(word_idx, char_idx, word_emb, char_emb,
                                             Wc, bc, Wih_f, b_f, Wih_b, b_b, gbuf);
    k_l<<<B_, 64, 0, stream>>>(Whh_f, Whh_b, gbuf, hbuf);
    k_p<<<(B_ * S_) / 64, 256, 0, stream>>>(hbuf, Wt, bt, (float*)d_out);
}

// Round 5
// 178.931 us; speedup vs baseline: 1.0399x; 1.0399x over previous
//
#include <hip/hip_runtime.h>

// Dims
#define B_   1024
#define S_   128
#define LP_  14
#define K_   3
#define CE_  6
#define WE_  10
#define LF_  4
#define H_   6
#define D_   14
#define T_   135
#define LW_  12
#define V_   50000
#define A_   100
#define NSEQ (B_ * 2)   // 2048 independent (sentence, direction) recurrences
#define PADR 16         // gbuf pad rows on EACH side (ring depth)

// Fast overflow-safe sigmoid/tanh (inf-propagation gives correct saturation).
static __device__ __forceinline__ float fsigm(float x) {
    return __frcp_rn(1.0f + __expf(-x));
}
static __device__ __forceinline__ float ftanh(float x) {
    return fmaf(2.0f, __frcp_rn(1.0f + __expf(-2.0f * x)), -1.0f);
}

// Wave64 all-lane sum via DPP (no DS traffic).
static __device__ __forceinline__ float wave_sum64(float s) {
    int v = __float_as_int(s);
    float f;
    f = __int_as_float(__builtin_amdgcn_update_dpp(0, v, 0xB1, 0xF, 0xF, true));  s += f; v = __float_as_int(s);
    f = __int_as_float(__builtin_amdgcn_update_dpp(0, v, 0x4E, 0xF, 0xF, true));  s += f; v = __float_as_int(s);
    f = __int_as_float(__builtin_amdgcn_update_dpp(0, v, 0x141, 0xF, 0xF, true)); s += f; v = __float_as_int(s);
    f = __int_as_float(__builtin_amdgcn_update_dpp(0, v, 0x140, 0xF, 0xF, true)); s += f; v = __float_as_int(s);
    f = __int_as_float(__builtin_amdgcn_update_dpp(0, v, 0x142, 0xA, 0xF, true)); s += f; v = __float_as_int(s);
    f = __int_as_float(__builtin_amdgcn_update_dpp(0, v, 0x143, 0xC, 0xF, true)); s += f; v = __float_as_int(s);
    return __int_as_float(__builtin_amdgcn_readlane(v, 63));
}

// ---------------- Kernel 1a: char CNN + embeddings + gate pre-activations (throughput) ----
// gbuf layout: [s][seq][unit u][gate j] -- UNIT-MAJOR so k_l reads ONE float4 per step.
// seq = 2*b + dir. 96 B per record, float4-aligned. gbuf points at row 0 of the DATA
// region (launcher allocates PADR pad rows on both sides for k_l's ring overrun).
__global__ __launch_bounds__(256) void k_e(
    const int* __restrict__ word_idx, const int* __restrict__ char_idx,
    const float* __restrict__ word_emb, const float* __restrict__ char_emb,
    const float* __restrict__ Wc, const float* __restrict__ bc,
    const float* __restrict__ Wih_f, const float* __restrict__ b_f,
    const float* __restrict__ Wih_b, const float* __restrict__ b_b,
    float* __restrict__ gbuf)
{
    __shared__ float s_ce[A_ * CE_];
    __shared__ float s_wc[LF_ * K_ * CE_];
    __shared__ float s_bc[LF_];
    int t = threadIdx.x;
    for (int e = t; e < A_ * CE_; e += 256) s_ce[e] = char_emb[e];
    if (t < LF_ * K_ * CE_) s_wc[t] = Wc[t];
    if (t < LF_) s_bc[t] = bc[t];
    __syncthreads();

    int wid = blockIdx.x * 256 + t;     // 0 .. 131071
    int s = wid >> 10;                  // 0 .. 127
    int b = wid & 1023;                 // 0 .. 1023
    int w = b * S_ + s;                 // row in word_idx/char_idx

    const int2* ci2 = (const int2*)(char_idx + (size_t)w * LP_);   // w*56B, 8B-aligned
    int idxs[LP_];
    #pragma unroll
    for (int p = 0; p < 7; ++p) {
        int2 v = ci2[p];
        idxs[2 * p] = v.x; idxs[2 * p + 1] = v.y;
    }
    float ce[LP_][CE_];
    #pragma unroll
    for (int p = 0; p < LP_; ++p) {
        int idx = idxs[p];
        idx = idx < 0 ? 0 : (idx >= A_ ? A_ - 1 : idx);
        #pragma unroll
        for (int c = 0; c < CE_; ++c) ce[p][c] = s_ce[idx * CE_ + c];
    }
    float x[D_];
    #pragma unroll
    for (int l = 0; l < LF_; ++l) {
        float acc[LW_];
        float bl = s_bc[l];
        #pragma unroll
        for (int q = 0; q < LW_; ++q) acc[q] = bl;
        #pragma unroll
        for (int kk = 0; kk < K_; ++kk) {
            #pragma unroll
            for (int c = 0; c < CE_; ++c) {
                float wv_ = s_wc[l * (K_ * CE_) + kk * CE_ + c];
                #pragma unroll
                for (int q = 0; q < LW_; ++q) acc[q] = fmaf(ce[q + kk][c], wv_, acc[q]);
            }
        }
        float m = acc[0];
        #pragma unroll
        for (int q = 1; q < LW_; ++q) m = fmaxf(m, acc[q]);
        x[WE_ + l] = m;
    }
    int wi = word_idx[w];
    wi = wi < 0 ? 0 : (wi >= V_ ? V_ - 1 : wi);
    const float2* wep = (const float2*)(word_emb + (size_t)wi * WE_);  // wi*40B, 8B-aligned
    #pragma unroll
    for (int c = 0; c < WE_ / 2; ++c) {
        float2 v = wep[c];
        x[2 * c] = v.x; x[2 * c + 1] = v.y;
    }

    // Gate pre-activations; record float4 #u = (i, f, g, o) of unit u (rows u, 6+u, 12+u, 18+u).
    float* dst = gbuf + ((size_t)s * NSEQ + 2 * b) * 24;   // fwd at +0, bwd at +24
    {
        float g[24];
        #pragma unroll
        for (int r = 0; r < 24; ++r) {
            float a = b_f[r];
            #pragma unroll
            for (int k = 0; k < D_; ++k) a = fmaf(Wih_f[r * D_ + k], x[k], a);
            g[r] = a;
        }
        #pragma unroll
        for (int u = 0; u < H_; ++u)
            ((float4*)dst)[u] = make_float4(g[u], g[H_ + u], g[2 * H_ + u], g[3 * H_ + u]);
    }
    {
        float g[24];
        #pragma unroll
        for (int r = 0; r < 24; ++r) {
            float a = b_b[r];
            #pragma unroll
            for (int k = 0; k < D_; ++k) a = fmaf(Wih_b[r * D_ + k], x[k], a);
            g[r] = a;
        }
        #pragma unroll
        for (int u = 0; u < H_; ++u)
            ((float4*)(dst + 24))[u] = make_float4(g[u], g[H_ + u], g[2 * H_ + u], g[3 * H_ + u]);
    }
}

// ---------------- Kernel 1b: BiLSTM recurrence (pipelined, branch-free body) ----------------
// Wave = one sentence: lanes 0-5 = fwd units, lanes 32-37 = bwd units (others shadow u=5).
// 1024 waves = 1 wave/SIMD chip-wide.
// KEY FIX vs R4: the 16-deep prefetch ring is refilled UNCONDITIONALLY (gbuf is padded
// PADR rows on both sides), and the loop body has NO branches (even the h-store is a
// benign duplicate write for shadow lanes). Straight-line VMEM issue/consume lets the
// waitcnt pass emit precise vmcnt(15) per consume instead of conservative full drains --
// load age = 16 steps ≈ 2400cy >> 900cy HBM latency, so loads fully pipeline.
__global__ __launch_bounds__(64) void k_l(
    const float* __restrict__ Whh_f, const float* __restrict__ Whh_b,
    const float* __restrict__ gbuf, float* __restrict__ hbuf)
{
    int lane = threadIdx.x;
    int dir  = lane >> 5;
    int u32  = lane & 31;
    int u    = (u32 < H_) ? u32 : (H_ - 1);   // shadow lanes replicate unit 5
    int b    = blockIdx.x;                     // sentence
    int seq  = 2 * b + dir;

    const float* Whh = dir ? Whh_b : Whh_f;
    float w0[H_], w1[H_], w2[H_], w3[H_];
    #pragma unroll
    for (int k = 0; k < H_; ++k) {
        w0[k] = Whh[(0 * H_ + u) * H_ + k];
        w1[k] = Whh[(1 * H_ + u) * H_ + k];
        w2[k] = Whh[(2 * H_ + u) * H_ + k];
        w3[k] = Whh[(3 * H_ + u) * H_ + k];
    }

    const long gstride = (dir ? -1L : 1L) * (long)(NSEQ * 24);
    const float* gp = gbuf + ((size_t)(dir ? S_ - 1 : 0) * NSEQ + (size_t)seq) * 24 + u * 4;

    // 16-deep prefetch ring (fully unrolled -> static VGPR indexing)
    float4 pf[PADR];
    #pragma unroll
    for (int j = 0; j < PADR; ++j) pf[j] = *(const float4*)(gp + j * gstride);
    const float* gn = gp + PADR * gstride;

    float* hp = hbuf + ((size_t)b * S_ + (size_t)(dir ? S_ - 1 : 0)) * 12 + dir * H_ + u;
    const int hstride = dir ? -12 : 12;

    float h[H_];
    #pragma unroll
    for (int k = 0; k < H_; ++k) h[k] = 0.f;
    float c = 0.f;

    #pragma unroll 1
    for (int m = 0; m < S_; m += PADR) {
        #pragma unroll
        for (int j = 0; j < PADR; ++j) {
            float4 g4 = pf[j];
            pf[j] = *(const float4*)gn;       // unconditional refill (pad rows absorb overrun)
            gn += gstride;

            float ai = g4.x, af = g4.y, ag = g4.z, ao = g4.w;
            #pragma unroll
            for (int k = 0; k < H_; ++k) {
                ai = fmaf(w0[k], h[k], ai);
                af = fmaf(w1[k], h[k], af);
                ag = fmaf(w2[k], h[k], ag);
                ao = fmaf(w3[k], h[k], ao);
            }
            float si = fsigm(ai), sf = fsigm(af), so = fsigm(ao), tg = ftanh(ag);
            c = fmaf(sf, c, si * tg);
            float hu = so * ftanh(c);

            *hp = hu;                          // shadow lanes duplicate lane 5's value: benign
            hp += hstride;

            // Broadcast via readlane (scalar pipe) + select. No DS ops, no branches.
            #pragma unroll
            for (int k = 0; k < H_; ++k) {
                int vf = __builtin_amdgcn_readlane(__float_as_int(hu), k);
                int vb = __builtin_amdgcn_readlane(__float_as_int(hu), 32 + k);
                h[k] = __int_as_float(dir ? vb : vf);
            }
        }
    }
}

// ---------------- Kernel 2: projection + log_softmax -> out f32 [B*S][135] ----------------
__global__ __launch_bounds__(256) void k_p(
    const float* __restrict__ hbuf,
    const float* __restrict__ Wt, const float* __restrict__ bt,
    float* __restrict__ out)
{
    __shared__ float s_hb[64 * 12];         // 3 KB
    int t = threadIdx.x;
    int ib = blockIdx.x * 64;               // first item of block
    {
        const float4* src = (const float4*)(hbuf + (size_t)ib * 12);
        float4* dst = (float4*)s_hb;
        if (t < 192) dst[t] = src[t];       // 64*12 floats = 192 float4, coalesced
    }
    __syncthreads();

    int lane = t & 63, wv = t >> 6;
    bool has2 = (lane < T_ - 128);
    int t2c = has2 ? (lane + 128) : (T_ - 1);

    float wA[12], wB[12], wC[12];
    #pragma unroll
    for (int jj = 0; jj < 12; ++jj) {
        wA[jj] = Wt[lane * 12 + jj];
        wB[jj] = Wt[(lane + 64) * 12 + jj];
        wC[jj] = Wt[t2c * 12 + jj];
    }
    float bA = bt[lane], bB = bt[lane + 64], bC = bt[t2c];

    int it0 = wv * 16;
    #pragma unroll 4
    for (int k = 0; k < 16; ++k) {
        int it = it0 + k;
        const float4* h4 = (const float4*)(s_hb + it * 12);   // broadcast LDS reads
        float4 a0 = h4[0], a1 = h4[1], a2 = h4[2];
        float hv[12] = {a0.x, a0.y, a0.z, a0.w, a1.x, a1.y, a1.z, a1.w, a2.x, a2.y, a2.z, a2.w};
        float y0 = bA, y1 = bB, y2 = bC;
        #pragma unroll
        for (int jj = 0; jj < 12; ++jj) {
            y0 = fmaf(hv[jj], wA[jj], y0);
            y1 = fmaf(hv[jj], wB[jj], y1);
            y2 = fmaf(hv[jj], wC[jj], y2);
        }
        // |y| small (h in (-1,1), weights ~0.1) -> exp safe without max-subtraction
        float ss = __expf(y0) + __expf(y1) + (has2 ? __expf(y2) : 0.0f);
        float ls = __logf(wave_sum64(ss));
        float* op = out + (size_t)(ib + it) * T_;
        op[lane]      = y0 - ls;
        op[lane + 64] = y1 - ls;
        if (has2) op[lane + 128] = y2 - ls;
    }
}

extern "C" void kernel_launch(void* const* d_in, const int* in_sizes, int n_in,
                              void* d_out, int out_size, void* d_ws, size_t ws_size,
                              hipStream_t stream)
{
    const int* word_idx = (const int*)d_in[0];
    const int* char_idx = (const int*)d_in[1];
    const float* word_emb = (const float*)d_in[2];
    const float* char_emb = (const float*)d_in[3];
    const float* Wc    = (const float*)d_in[4];
    const float* bc    = (const float*)d_in[5];
    const float* Wih_f = (const float*)d_in[6];
    const float* Whh_f = (const float*)d_in[7];
    const float* b_f   = (const float*)d_in[8];
    const float* Wih_b = (const float*)d_in[9];
    const float* Whh_b = (const float*)d_in[10];
    const float* b_b   = (const float*)d_in[11];
    const float* Wt    = (const float*)d_in[12];
    const float* bt    = (const float*)d_in[13];

    const size_t hbuf_fl = (size_t)B_ * S_ * 12;                   // 6.3 MB
    const size_t grow_fl = (size_t)NSEQ * 24;                      // one step-row
    const size_t galloc_fl = (size_t)(S_ + 2 * PADR) * grow_fl;    // padded: 31.5 MB

    float* hbuf = (float*)d_ws;
    float* galloc;
    if (ws_size >= (hbuf_fl + galloc_fl) * sizeof(float)) {
        galloc = (float*)d_ws + hbuf_fl;
    } else {
        // scratch inside d_out (70.8 MB >= 31.5 MB): k_e writes, k_l reads, then k_p
        // overwrites every element of d_out. Stream-ordered, so this is safe.
        galloc = (float*)d_out;
    }
    float* gbuf = galloc + PADR * grow_fl;   // data region; PADR pad rows on both sides

    k_e<<<(B_ * S_) / 256, 256, 0, stream>>>(word_idx, char_idx, word_emb, char_emb,
                                             Wc, bc, Wih_f, b_f, Wih_b, b_b, gbuf);
    k_l<<<B_, 64, 0, stream>>>(Whh_f, Whh_b, gbuf, hbuf);
    k_p<<<(B_ * S_) / 64, 256, 0, stream>>>(hbuf, Wt, bt, (float*)d_out);
}